// Round 11
// baseline (763.417 us; speedup 1.0000x reference)
//
#include <hip/hip_runtime.h>

#define P1 46
#define P2 52
#define IS2 0.70710678118654752f

__device__ __forceinline__ int symidx(int t, int n) {
    t = (t < 0) ? (-1 - t) : t;
    return (t >= n) ? (2 * n - 1 - t) : t;
}

#define SB() __builtin_amdgcn_sched_barrier(0)

// ================= border-path helpers (r1/r8, proven) =================
__device__ __forceinline__ void col13_yl(
    float (&acc)[32], const float* __restrict__ ylp,
    const float* __restrict__ taps, int r0, int cc)
{
    #pragma unroll
    for (int pi = 0; pi < 44; ++pi) {
        int rr = symidx(r0 - 6 + pi, 256);
        float v = ylp[rr * 256 + cc];
        #pragma unroll
        for (int j = 0; j < 13; ++j) {
            int ro = pi + j - 12;
            if (ro >= 0 && ro < 32) acc[ro] = fmaf(taps[j], v, acc[ro]);
        }
    }
}

__device__ __forceinline__ void col13_c2q(
    float (&acc)[32], const float* __restrict__ yhr, const float* __restrict__ yhi,
    int bA, int bB, const float* __restrict__ taps, int r0, int cc)
{
    const int cp = cc & 1;
    const int j2 = cc >> 1;
    #pragma unroll
    for (int pi = 0; pi < 44; ++pi) {
        int rr = symidx(r0 - 6 + pi, 256);
        int rp = rr & 1;
        int i2 = rr >> 1;
        const float* base = (((rp ^ cp) != 0) ? yhi : yhr) + (i2 * 128 + j2);
        float A  = base[bA * 16384];
        float Bv = base[bB * 16384];
        float vA = (rp & cp)       ? -A  : A;
        float vB = (rp & (cp ^ 1)) ? -Bv : Bv;
        float v = (vA + vB) * IS2;
        #pragma unroll
        for (int j = 0; j < 13; ++j) {
            int ro = pi + j - 12;
            if (ro >= 0 && ro < 32) acc[ro] = fmaf(taps[j], v, acc[ro]);
        }
    }
}

// lh border, row range [PI0, PI1)
template<int PI0, int PI1>
__device__ __forceinline__ void col19_c2q_rng(
    float (&acc)[32], const float* __restrict__ yhr, const float* __restrict__ yhi,
    const float* __restrict__ taps, int r0, int cc)
{
    const int cp = cc & 1;
    const int j2 = cc >> 1;
    #pragma unroll
    for (int pi = PI0; pi < PI1; ++pi) {
        int rr = symidx(r0 - 9 + pi, 256);
        int rp = rr & 1;
        int i2 = rr >> 1;
        const float* base = (((rp ^ cp) != 0) ? yhi : yhr) + (i2 * 128 + j2);
        float A  = base[0 * 16384];
        float Bv = base[5 * 16384];
        float vA = (rp & cp)       ? -A  : A;
        float vB = (rp & (cp ^ 1)) ? -Bv : Bv;
        float v = (vA + vB) * IS2;
        #pragma unroll
        for (int j = 0; j < 19; ++j) {
            int ro = pi + j - 18;
            if (ro >= 0 && ro < 32) acc[ro] = fmaf(taps[j], v, acc[ro]);
        }
    }
}

// ================= interior pipelined helpers (r8, proven) =================
template<int NU>
__device__ __forceinline__ void load_pairs(float* buf,
    const float* __restrict__ pEA, const float* __restrict__ pEB,
    const float* __restrict__ pOA, const float* __restrict__ pOB,
    int vof)
{
    #pragma unroll
    for (int u = 0; u < NU; ++u) {
        buf[4*u+0] = pEA[vof + u * 128];
        buf[4*u+1] = pEB[vof + u * 128];
        buf[4*u+2] = pOA[vof + u * 128];
        buf[4*u+3] = pOB[vof + u * 128];
    }
}

template<int L, int EPI0, int UB, int NU>
__device__ __forceinline__ void consume_pairs(float (&acc)[32], const float* buf,
                                              float sgn, const float* __restrict__ taps)
{
    #pragma unroll
    for (int u = 0; u < NU; ++u) {
        float ve = (buf[4*u+0] + buf[4*u+1]) * IS2;
        float vo = (buf[4*u+2] - buf[4*u+3]) * sgn;
        const int pi = EPI0 + 2 * (UB + u);
        #pragma unroll
        for (int j = 0; j < L; ++j) {
            int ro = pi + j - (L - 1);
            if (ro >= 0 && ro < 32) acc[ro] = fmaf(taps[j], ve, acc[ro]);
        }
        #pragma unroll
        for (int j = 0; j < L; ++j) {
            int ro = pi + 1 + j - (L - 1);
            if (ro >= 0 && ro < 32) acc[ro] = fmaf(taps[j], vo, acc[ro]);
        }
    }
}

// pipelined c2q column filter: NPT pairs (chunks C,C,C,rest), pair index offset UOFF
template<int L, int EPI0, int UOFF, int NPT, int C>
__device__ __forceinline__ void c2q_col_pipe(
    float (&acc)[32],
    const float* __restrict__ pEA, const float* __restrict__ pEB,
    const float* __restrict__ pOA, const float* __restrict__ pOB,
    int vof, float sgn, const float* __restrict__ taps)
{
    float bufA[4 * C], bufB[4 * C];
    constexpr int R = NPT - 3 * C;
    static_assert(R > 0 && R <= C, "chunking");
    load_pairs<C>(bufA, pEA, pEB, pOA, pOB, vof);
    SB();
    load_pairs<C>(bufB, pEA, pEB, pOA, pOB, vof + C * 128);
    SB();
    consume_pairs<L, EPI0, UOFF + 0, C>(acc, bufA, sgn, taps);
    SB();
    load_pairs<C>(bufA, pEA, pEB, pOA, pOB, vof + 2 * C * 128);
    SB();
    consume_pairs<L, EPI0, UOFF + C, C>(acc, bufB, sgn, taps);
    SB();
    load_pairs<R>(bufB, pEA, pEB, pOA, pOB, vof + 3 * C * 128);
    SB();
    consume_pairs<L, EPI0, UOFF + 2 * C, C>(acc, bufA, sgn, taps);
    SB();
    consume_pairs<L, EPI0, UOFF + 3 * C, R>(acc, bufB, sgn, taps);
}

template<int NT>
__device__ __forceinline__ void load_rows(float (&buf)[11], const float* __restrict__ p, int t0)
{
    #pragma unroll
    for (int t = 0; t < NT; ++t) buf[t] = p[(t0 + t) * 256];
}

template<int TB, int NT>
__device__ __forceinline__ void consume_rows(float (&acc)[32], const float (&buf)[11],
                                             const float* __restrict__ taps)
{
    #pragma unroll
    for (int t = 0; t < NT; ++t) {
        float v = buf[t];
        const int pi = TB + t;
        #pragma unroll
        for (int j = 0; j < 13; ++j) {
            int ro = pi + j - 12;
            if (ro >= 0 && ro < 32) acc[ro] = fmaf(taps[j], v, acc[ro]);
        }
    }
}

extern "C" __global__ __launch_bounds__(320, 4) void dtcwt_inv(
    const float* __restrict__ Yl, const float* __restrict__ Yhr,
    const float* __restrict__ Yhi,
    const float* __restrict__ g0, const float* __restrict__ g1,
    const float* __restrict__ g2, float* __restrict__ out)
{
    // t1 = col_g0(Yl) + col_g1(lh); t2 = col_g0(hl); t3 = col_g2(hh)
    __shared__ __align__(16) float sU1[32][P1];   // cols <-> img c0-6+ti
    __shared__ __align__(16) float sU2[32][P2];   // cols <-> img c0-9+ti
    __shared__ __align__(16) float sU3[32][P1];   // cols <-> img c0-6+ti

    const int tid = threadIdx.x;
    // bijective XCD swizzle: 32768 = 8 x 4096; 64 planes per XCD chunk
    const int wg  = blockIdx.x;
    const int swz = (wg & 7) * 4096 + (wg >> 3);
    const int plane = swz >> 6;
    const int bt = swz & 63;
    const int bx = bt & 7;
    const int by = bt >> 3;
    const int r0 = by * 32;
    const int c0 = bx * 32;

    const float* ylp = Yl  + (size_t)plane * 65536;
    const float* yhr = Yhr + (size_t)plane * 6 * 16384;
    const float* yhi = Yhi + (size_t)plane * 6 * 16384;

    const bool rowInterior = (by >= 1) && (by <= 6);

    const int w    = tid >> 6;
    const int lane = tid & 63;

    float acc[32];
    #pragma unroll
    for (int i = 0; i < 32; ++i) acc[i] = 0.0f;

    bool lhAct = false;

    if (w == 0) {
        if (lane < 44) {                 // Yl -> t1 (store)
            int cc = symidx(c0 - 6 + lane, 256);
            if (rowInterior) {
                const float* p = ylp + (r0 - 6) * 256 + cc;
                float bufA[11], bufB[11];
                load_rows<11>(bufA, p, 0);
                SB();
                load_rows<11>(bufB, p, 11);
                SB();
                consume_rows<0, 11>(acc, bufA, g0);
                SB();
                load_rows<11>(bufA, p, 22);
                SB();
                consume_rows<11, 11>(acc, bufB, g0);
                SB();
                load_rows<11>(bufB, p, 33);
                SB();
                consume_rows<22, 11>(acc, bufA, g0);
                SB();
                consume_rows<33, 11>(acc, bufB, g0);
            } else {
                col13_yl(acc, ylp, g0, r0, cc);
            }
            #pragma unroll
            for (int ro = 0; ro < 32; ++ro) sU1[ro][lane] = acc[ro];
        }
    } else if (w == 1 || w == 2) {
        if (lane < 44) {                 // lh split-K halves (defer-add into t1)
            lhAct = true;
            int cc = symidx(c0 - 6 + lane, 256);
            if (rowInterior) {
                int cp = cc & 1, j2 = cc >> 1;
                const float* pE = cp ? yhi : yhr;
                const float* pO = cp ? yhr : yhi;
                float sgn = cp ? -IS2 : IS2;
                int vof = ((r0 - 10) >> 1) * 128 + j2;
                if (w == 1)
                    c2q_col_pipe<19, -1, 0, 13, 4>(acc,
                        pE + 0 * 16384, pE + 5 * 16384,
                        pO + 0 * 16384, pO + 5 * 16384, vof, sgn, g1);
                else
                    c2q_col_pipe<19, -1, 13, 13, 4>(acc,
                        pE + 0 * 16384, pE + 5 * 16384,
                        pO + 0 * 16384, pO + 5 * 16384, vof + 13 * 128, sgn, g1);
            } else {
                if (w == 1) col19_c2q_rng<0, 25>(acc, yhr, yhi, g1, r0, cc);
                else        col19_c2q_rng<25, 50>(acc, yhr, yhi, g1, r0, cc);
            }
        }
    } else if (w == 3) {
        if (lane < 50) {                 // hl -> t2
            int cc = symidx(c0 - 9 + lane, 256);
            if (rowInterior) {
                int cp = cc & 1, j2 = cc >> 1;
                const float* pE = cp ? yhi : yhr;
                const float* pO = cp ? yhr : yhi;
                float sgn = cp ? -IS2 : IS2;
                int vof = ((r0 - 6) >> 1) * 128 + j2;
                c2q_col_pipe<13, 0, 0, 22, 6>(acc,
                    pE + 2 * 16384, pE + 3 * 16384,
                    pO + 2 * 16384, pO + 3 * 16384, vof, sgn, g0);
            } else {
                col13_c2q(acc, yhr, yhi, 2, 3, g0, r0, cc);
            }
            #pragma unroll
            for (int ro = 0; ro < 32; ++ro) sU2[ro][lane] = acc[ro];
        }
    } else {
        if (lane < 44) {                 // hh -> t3
            int cc = symidx(c0 - 6 + lane, 256);
            if (rowInterior) {
                int cp = cc & 1, j2 = cc >> 1;
                const float* pE = cp ? yhi : yhr;
                const float* pO = cp ? yhr : yhi;
                float sgn = cp ? -IS2 : IS2;
                int vof = ((r0 - 6) >> 1) * 128 + j2;
                c2q_col_pipe<13, 0, 0, 22, 6>(acc,
                    pE + 1 * 16384, pE + 4 * 16384,
                    pO + 1 * 16384, pO + 4 * 16384, vof, sgn, g2);
            } else {
                col13_c2q(acc, yhr, yhi, 1, 4, g2, r0, cc);
            }
            #pragma unroll
            for (int ro = 0; ro < 32; ++ro) sU3[ro][lane] = acc[ro];
        }
    }
    __syncthreads();

    // lh halves accumulate into t1 (ds_add_f32; distinct addresses per lane,
    // w1/w2 collisions serialized by HW)
    if (lhAct) {
        #pragma unroll
        for (int ro = 0; ro < 32; ++ro) atomicAdd(&sU1[ro][lane], acc[ro]);
    }

    // stage-2 lanes prefetch t2/t3 windows (final since barrier 1)
    const int r2 = (tid & 255) >> 3;
    const int cg = tid & 7;
    const int cb = 4 * cg;

    float w2v[22], w3v[16];
    if (tid < 256) {
        #pragma unroll
        for (int k = 0; k < 11; ++k) {
            float2 a = *(const float2*)&sU2[r2][cb + 2 * k];
            w2v[2*k] = a.x; w2v[2*k+1] = a.y;
        }
        #pragma unroll
        for (int k = 0; k < 8; ++k) {
            float2 a = *(const float2*)&sU3[r2][cb + 2 * k];
            w3v[2*k] = a.x; w3v[2*k+1] = a.y;
        }
    }
    __syncthreads();

    if (tid < 256) {
        float w1v[16];
        #pragma unroll
        for (int k = 0; k < 8; ++k) {
            float2 a = *(const float2*)&sU1[r2][cb + 2 * k];
            w1v[2*k] = a.x; w1v[2*k+1] = a.y;
        }

        float4 res;
        float* op = (float*)&res;
        #pragma unroll
        for (int q = 0; q < 4; ++q) {
            float s = 0.0f;
            #pragma unroll
            for (int j = 0; j < 13; ++j) s = fmaf(g0[j], w1v[q + 12 - j], s);
            #pragma unroll
            for (int j = 0; j < 19; ++j) s = fmaf(g1[j], w2v[q + 18 - j], s);
            #pragma unroll
            for (int j = 0; j < 13; ++j) s = fmaf(g2[j], w3v[q + 12 - j], s);
            op[q] = s;
        }
        *(float4*)&out[(size_t)plane * 65536 + (size_t)(r0 + r2) * 256 + (c0 + cb)] = res;
    }
}

extern "C" void kernel_launch(void* const* d_in, const int* in_sizes, int n_in,
                              void* d_out, int out_size, void* d_ws, size_t ws_size,
                              hipStream_t stream) {
    const float* Yl  = (const float*)d_in[0];
    const float* Yhr = (const float*)d_in[1];
    const float* Yhi = (const float*)d_in[2];
    const float* g0  = (const float*)d_in[3];
    const float* g1  = (const float*)d_in[4];
    const float* g2  = (const float*)d_in[5];
    float* out = (float*)d_out;

    dim3 grid(32768, 1, 1);   // 8x8 tiles x 512 planes, XCD-swizzled in-kernel
    dim3 block(320, 1, 1);
    dtcwt_inv<<<grid, block, 0, stream>>>(Yl, Yhr, Yhi, g0, g1, g2, out);
}

// Round 12
// 317.596 us; speedup vs baseline: 2.4037x; 2.4037x over previous
//
#include <hip/hip_runtime.h>

#define PW 90
#define IS2 0.70710678118654752f

__device__ __forceinline__ int symidx(int t, int n) {
    t = (t < 0) ? (-1 - t) : t;
    return (t >= n) ? (2 * n - 1 - t) : t;
}

#define SB() __builtin_amdgcn_sched_barrier(0)

// ================= border-path helpers (r1, proven) =================
__device__ __forceinline__ void col13_yl(
    float (&acc)[32], const float* __restrict__ ylp,
    const float* __restrict__ taps, int r0, int cc)
{
    #pragma unroll
    for (int pi = 0; pi < 44; ++pi) {
        int rr = symidx(r0 - 6 + pi, 256);
        float v = ylp[rr * 256 + cc];
        #pragma unroll
        for (int j = 0; j < 13; ++j) {
            int ro = pi + j - 12;
            if (ro >= 0 && ro < 32) acc[ro] = fmaf(taps[j], v, acc[ro]);
        }
    }
}

__device__ __forceinline__ void col13_c2q(
    float (&acc)[32], const float* __restrict__ yhr, const float* __restrict__ yhi,
    int bA, int bB, const float* __restrict__ taps, int r0, int cc)
{
    const int cp = cc & 1;
    const int j2 = cc >> 1;
    #pragma unroll
    for (int pi = 0; pi < 44; ++pi) {
        int rr = symidx(r0 - 6 + pi, 256);
        int rp = rr & 1;
        int i2 = rr >> 1;
        const float* base = (((rp ^ cp) != 0) ? yhi : yhr) + (i2 * 128 + j2);
        float A  = base[bA * 16384];
        float Bv = base[bB * 16384];
        float vA = (rp & cp)       ? -A  : A;
        float vB = (rp & (cp ^ 1)) ? -Bv : Bv;
        float v = (vA + vB) * IS2;
        #pragma unroll
        for (int j = 0; j < 13; ++j) {
            int ro = pi + j - 12;
            if (ro >= 0 && ro < 32) acc[ro] = fmaf(taps[j], v, acc[ro]);
        }
    }
}

__device__ __forceinline__ void col19_c2q(
    float (&acc)[32], const float* __restrict__ yhr, const float* __restrict__ yhi,
    const float* __restrict__ taps, int r0, int cc)
{
    const int bA = 0, bB = 5;
    const int cp = cc & 1;
    const int j2 = cc >> 1;
    #pragma unroll
    for (int pi = 0; pi < 50; ++pi) {
        int rr = symidx(r0 - 9 + pi, 256);
        int rp = rr & 1;
        int i2 = rr >> 1;
        const float* base = (((rp ^ cp) != 0) ? yhi : yhr) + (i2 * 128 + j2);
        float A  = base[0 * 16384];
        float Bv = base[5 * 16384];
        float vA = (rp & cp)       ? -A  : A;
        float vB = (rp & (cp ^ 1)) ? -Bv : Bv;
        float v = (vA + vB) * IS2;
        #pragma unroll
        for (int j = 0; j < 19; ++j) {
            int ro = pi + j - 18;
            if (ro >= 0 && ro < 32) acc[ro] = fmaf(taps[j], v, acc[ro]);
        }
    }
}

// ================= interior pipelined helpers =================
template<int NU>
__device__ __forceinline__ void load_pairs(float* buf,
    const float* __restrict__ pEA, const float* __restrict__ pEB,
    const float* __restrict__ pOA, const float* __restrict__ pOB,
    int vof)
{
    #pragma unroll
    for (int u = 0; u < NU; ++u) {
        buf[4*u+0] = pEA[vof + u * 128];
        buf[4*u+1] = pEB[vof + u * 128];
        buf[4*u+2] = pOA[vof + u * 128];
        buf[4*u+3] = pOB[vof + u * 128];
    }
}

template<int L, int EPI0, int UB, int NU>
__device__ __forceinline__ void consume_pairs(float (&acc)[32], const float* buf,
                                              float sgn, const float* __restrict__ taps)
{
    #pragma unroll
    for (int u = 0; u < NU; ++u) {
        float ve = (buf[4*u+0] + buf[4*u+1]) * IS2;
        float vo = (buf[4*u+2] - buf[4*u+3]) * sgn;
        const int pi = EPI0 + 2 * (UB + u);
        #pragma unroll
        for (int j = 0; j < L; ++j) {
            int ro = pi + j - (L - 1);
            if (ro >= 0 && ro < 32) acc[ro] = fmaf(taps[j], ve, acc[ro]);
        }
        #pragma unroll
        for (int j = 0; j < L; ++j) {
            int ro = pi + 1 + j - (L - 1);
            if (ro >= 0 && ro < 32) acc[ro] = fmaf(taps[j], vo, acc[ro]);
        }
    }
}

// depth-2 pipelined c2q column filter: chunks {N0,C,C,C,C}, 3 rotating buffers.
// Each consumed chunk was issued >=2 consume-phases earlier (~2*C*2L cyc cover).
template<int L, int EPI0, int NPT, int C>
__device__ __forceinline__ void c2q_pipe3(
    float (&acc)[32],
    const float* __restrict__ pEA, const float* __restrict__ pEB,
    const float* __restrict__ pOA, const float* __restrict__ pOB,
    int vof, float sgn, const float* __restrict__ taps)
{
    constexpr int N0 = NPT - 4 * C;
    static_assert(N0 > 0 && N0 <= 8, "chunking");
    constexpr int A0 = 0, B0 = N0, C0 = N0 + C, A1 = N0 + 2 * C, B1 = N0 + 3 * C;
    float bufA[4 * ((N0 > C) ? N0 : C)], bufB[4 * C], bufC[4 * C];
    load_pairs<N0>(bufA, pEA, pEB, pOA, pOB, vof + A0 * 128);
    SB();
    load_pairs<C>(bufB, pEA, pEB, pOA, pOB, vof + B0 * 128);
    SB();
    load_pairs<C>(bufC, pEA, pEB, pOA, pOB, vof + C0 * 128);
    SB();
    consume_pairs<L, EPI0, A0, N0>(acc, bufA, sgn, taps);
    SB();
    load_pairs<C>(bufA, pEA, pEB, pOA, pOB, vof + A1 * 128);
    SB();
    consume_pairs<L, EPI0, B0, C>(acc, bufB, sgn, taps);
    SB();
    load_pairs<C>(bufB, pEA, pEB, pOA, pOB, vof + B1 * 128);
    SB();
    consume_pairs<L, EPI0, C0, C>(acc, bufC, sgn, taps);
    SB();
    consume_pairs<L, EPI0, A1, C>(acc, bufA, sgn, taps);
    SB();
    consume_pairs<L, EPI0, B1, C>(acc, bufB, sgn, taps);
}

template<int NT>
__device__ __forceinline__ void load_rows(float* buf, const float* __restrict__ p, int t0)
{
    #pragma unroll
    for (int t = 0; t < NT; ++t) buf[t] = p[(t0 + t) * 256];
}

template<int TB, int NT>
__device__ __forceinline__ void consume_rows(float (&acc)[32], const float* buf,
                                             const float* __restrict__ taps)
{
    #pragma unroll
    for (int t = 0; t < NT; ++t) {
        float v = buf[t];
        const int pi = TB + t;
        #pragma unroll
        for (int j = 0; j < 13; ++j) {
            int ro = pi + j - 12;
            if (ro >= 0 && ro < 32) acc[ro] = fmaf(taps[j], v, acc[ro]);
        }
    }
}

// depth-2 Yl pipe: 44 rows in chunks {4,10,10,10,10}, 3 rotating buffers
__device__ __forceinline__ void yl_pipe3(float (&acc)[32], const float* __restrict__ p,
                                         const float* __restrict__ g0)
{
    float bufA[10], bufB[10], bufC[10];
    load_rows<4>(bufA, p, 0);
    SB();
    load_rows<10>(bufB, p, 4);
    SB();
    load_rows<10>(bufC, p, 14);
    SB();
    consume_rows<0, 4>(acc, bufA, g0);
    SB();
    load_rows<10>(bufA, p, 24);
    SB();
    consume_rows<4, 10>(acc, bufB, g0);
    SB();
    load_rows<10>(bufB, p, 34);
    SB();
    consume_rows<14, 10>(acc, bufC, g0);
    SB();
    consume_rows<24, 10>(acc, bufA, g0);
    SB();
    consume_rows<34, 10>(acc, bufB, g0);
}

extern "C" __global__ __launch_bounds__(512, 4) void dtcwt_inv(
    const float* __restrict__ Yl, const float* __restrict__ Yhr,
    const float* __restrict__ Yhi,
    const float* __restrict__ g0, const float* __restrict__ g1,
    const float* __restrict__ g2, float* __restrict__ out)
{
    // sU[0] = t1a (+t1b added after barrier1), sU[1] = t2 (hl), sU[2] = t3 (hh)
    __shared__ __align__(16) float sU[3][32][PW];   // 34560 B

    const int tid = threadIdx.x;
    // bijective XCD swizzle: 16384 = 8 x 2048
    const int wg  = blockIdx.x;
    const int swz = (wg & 7) * 2048 + (wg >> 3);
    const int plane = swz >> 5;
    const int bt = swz & 31;
    const int bx = bt & 3;
    const int by = bt >> 2;
    const int r0 = by * 32;
    const int c0 = bx * 64;

    const float* ylp = Yl  + (size_t)plane * 65536;
    const float* yhr = Yhr + (size_t)plane * 6 * 16384;
    const float* yhi = Yhi + (size_t)plane * 6 * 16384;

    const bool rowInterior = (by >= 1) && (by <= 6);

    const int role = tid >> 7;
    const int lr   = tid & 127;

    float acc[32];
    #pragma unroll
    for (int i = 0; i < 32; ++i) acc[i] = 0.0f;
    int ti = -1;

    if (rowInterior) {
        if (role == 0) {
            if (lr < 76) {
                ti = lr + 6;
                int cc = symidx(c0 + lr - 6, 256);
                yl_pipe3(acc, ylp + (r0 - 6) * 256 + cc, g0);
            }
        } else if (role == 1) {
            if (lr < 76) {                        // t1b = col_g1(lh), bands 0,5
                ti = lr + 6;
                int cc = symidx(c0 + lr - 6, 256);
                int cp = cc & 1, j2 = cc >> 1;
                const float* pE = cp ? yhi : yhr;
                const float* pO = cp ? yhr : yhi;
                float sgn = cp ? -IS2 : IS2;
                int vof = ((r0 - 10) >> 1) * 128 + j2;
                c2q_pipe3<19, -1, 26, 5>(acc,
                    pE + 0 * 16384, pE + 5 * 16384,
                    pO + 0 * 16384, pO + 5 * 16384, vof, sgn, g1);
            }
        } else if (role == 2) {
            if (lr < 82) {                        // t2 = col_g0(hl), bands 2,3
                ti = lr + 3;
                int cc = symidx(c0 + lr - 9, 256);
                int cp = cc & 1, j2 = cc >> 1;
                const float* pE = cp ? yhi : yhr;
                const float* pO = cp ? yhr : yhi;
                float sgn = cp ? -IS2 : IS2;
                int vof = ((r0 - 6) >> 1) * 128 + j2;
                c2q_pipe3<13, 0, 22, 5>(acc,
                    pE + 2 * 16384, pE + 3 * 16384,
                    pO + 2 * 16384, pO + 3 * 16384, vof, sgn, g0);
            }
        } else {
            if (lr < 76) {                        // t3 = col_g2(hh), bands 1,4
                ti = lr + 6;
                int cc = symidx(c0 + lr - 6, 256);
                int cp = cc & 1, j2 = cc >> 1;
                const float* pE = cp ? yhi : yhr;
                const float* pO = cp ? yhr : yhi;
                float sgn = cp ? -IS2 : IS2;
                int vof = ((r0 - 6) >> 1) * 128 + j2;
                c2q_pipe3<13, 0, 22, 5>(acc,
                    pE + 1 * 16384, pE + 4 * 16384,
                    pO + 1 * 16384, pO + 4 * 16384, vof, sgn, g2);
            }
        }
    } else {
        // ---------- border stage 1 (r1 path, handles row reflection) ----------
        if (role == 0) {
            if (lr < 76) {
                ti = lr + 6;
                int cc = symidx(c0 + ti - 12, 256);
                col13_yl(acc, ylp, g0, r0, cc);
            }
        } else if (role == 1) {
            if (lr < 76) {
                ti = lr + 6;
                int cc = symidx(c0 + ti - 12, 256);
                col19_c2q(acc, yhr, yhi, g1, r0, cc);
            }
        } else if (role == 2) {
            if (lr < 82) {
                ti = lr + 3;
                int cc = symidx(c0 + ti - 12, 256);
                col13_c2q(acc, yhr, yhi, 2, 3, g0, r0, cc);
            }
        } else {
            if (lr < 76) {
                ti = lr + 6;
                int cc = symidx(c0 + ti - 12, 256);
                col13_c2q(acc, yhr, yhi, 1, 4, g2, r0, cc);
            }
        }
    }

    // direct writers: role0 -> sU[0], role2 -> sU[1], role3 -> sU[2]
    if (ti >= 0 && role != 1) {
        const int bi = (role == 0) ? 0 : (role == 2 ? 1 : 2);
        #pragma unroll
        for (int ro = 0; ro < 32; ++ro) sU[bi][ro][ti] = acc[ro];
    }
    __syncthreads();

    // deferred add: lh accumulates into t1 buffer (2 waves only)
    if (role == 1 && ti >= 0) {
        #pragma unroll
        for (int ro = 0; ro < 32; ++ro) sU[0][ro][ti] += acc[ro];
    }

    // meanwhile all waves prefetch w2/w3 (untouched buffers)
    const int cg = tid & 15;
    const int r2 = tid >> 4;
    const int cb = 4 * cg;

    float w2v[28];
    #pragma unroll
    for (int k = 0; k < 14; ++k) {
        float2 a = *(const float2*)&sU[1][r2][cb + 2 * k];
        w2v[2*k] = a.x; w2v[2*k+1] = a.y;
    }
    float w3v[20];
    #pragma unroll
    for (int k = 0; k < 10; ++k) {
        float2 a = *(const float2*)&sU[2][r2][cb + 4 + 2 * k];
        w3v[2*k] = a.x; w3v[2*k+1] = a.y;
    }
    __syncthreads();

    float w1v[20];
    #pragma unroll
    for (int k = 0; k < 10; ++k) {
        float2 a = *(const float2*)&sU[0][r2][cb + 4 + 2 * k];
        w1v[2*k] = a.x; w1v[2*k+1] = a.y;
    }

    float4 res;
    float* op = (float*)&res;
    #pragma unroll
    for (int q = 0; q < 4; ++q) {
        float s = 0.0f;
        #pragma unroll
        for (int j = 0; j < 13; ++j) s = fmaf(g0[j], w1v[q + 14 - j], s);
        #pragma unroll
        for (int j = 0; j < 19; ++j) s = fmaf(g1[j], w2v[q + 21 - j], s);
        #pragma unroll
        for (int j = 0; j < 13; ++j) s = fmaf(g2[j], w3v[q + 14 - j], s);
        op[q] = s;
    }
    *(float4*)&out[(size_t)plane * 65536 + (size_t)(r0 + r2) * 256 + (c0 + cb)] = res;
}

extern "C" void kernel_launch(void* const* d_in, const int* in_sizes, int n_in,
                              void* d_out, int out_size, void* d_ws, size_t ws_size,
                              hipStream_t stream) {
    const float* Yl  = (const float*)d_in[0];
    const float* Yhr = (const float*)d_in[1];
    const float* Yhi = (const float*)d_in[2];
    const float* g0  = (const float*)d_in[3];
    const float* g1  = (const float*)d_in[4];
    const float* g2  = (const float*)d_in[5];
    float* out = (float*)d_out;

    dim3 grid(16384, 1, 1);
    dim3 block(512, 1, 1);
    dtcwt_inv<<<grid, block, 0, stream>>>(Yl, Yhr, Yhi, g0, g1, g2, out);
}

// Round 13
// 313.153 us; speedup vs baseline: 2.4378x; 1.0142x over previous
//
#include <hip/hip_runtime.h>

#define PW 90
#define IS2 0.70710678118654752f

__device__ __forceinline__ int symidx(int t, int n) {
    t = (t < 0) ? (-1 - t) : t;
    return (t >= n) ? (2 * n - 1 - t) : t;
}

#define SB() __builtin_amdgcn_sched_barrier(0)

// ================= border-path helpers (r1, proven) =================
__device__ __forceinline__ void col13_yl(
    float (&acc)[32], const float* __restrict__ ylp,
    const float* __restrict__ taps, int r0, int cc)
{
    #pragma unroll
    for (int pi = 0; pi < 44; ++pi) {
        int rr = symidx(r0 - 6 + pi, 256);
        float v = ylp[rr * 256 + cc];
        #pragma unroll
        for (int j = 0; j < 13; ++j) {
            int ro = pi + j - 12;
            if (ro >= 0 && ro < 32) acc[ro] = fmaf(taps[j], v, acc[ro]);
        }
    }
}

__device__ __forceinline__ void col13_c2q(
    float (&acc)[32], const float* __restrict__ yhr, const float* __restrict__ yhi,
    int bA, int bB, const float* __restrict__ taps, int r0, int cc)
{
    const int cp = cc & 1;
    const int j2 = cc >> 1;
    #pragma unroll
    for (int pi = 0; pi < 44; ++pi) {
        int rr = symidx(r0 - 6 + pi, 256);
        int rp = rr & 1;
        int i2 = rr >> 1;
        const float* base = (((rp ^ cp) != 0) ? yhi : yhr) + (i2 * 128 + j2);
        float A  = base[bA * 16384];
        float Bv = base[bB * 16384];
        float vA = (rp & cp)       ? -A  : A;
        float vB = (rp & (cp ^ 1)) ? -Bv : Bv;
        float v = (vA + vB) * IS2;
        #pragma unroll
        for (int j = 0; j < 13; ++j) {
            int ro = pi + j - 12;
            if (ro >= 0 && ro < 32) acc[ro] = fmaf(taps[j], v, acc[ro]);
        }
    }
}

__device__ __forceinline__ void col19_c2q(
    float (&acc)[32], const float* __restrict__ yhr, const float* __restrict__ yhi,
    const float* __restrict__ taps, int r0, int cc)
{
    const int cp = cc & 1;
    const int j2 = cc >> 1;
    #pragma unroll
    for (int pi = 0; pi < 50; ++pi) {
        int rr = symidx(r0 - 9 + pi, 256);
        int rp = rr & 1;
        int i2 = rr >> 1;
        const float* base = (((rp ^ cp) != 0) ? yhi : yhr) + (i2 * 128 + j2);
        float A  = base[0 * 16384];
        float Bv = base[5 * 16384];
        float vA = (rp & cp)       ? -A  : A;
        float vB = (rp & (cp ^ 1)) ? -Bv : Bv;
        float v = (vA + vB) * IS2;
        #pragma unroll
        for (int j = 0; j < 19; ++j) {
            int ro = pi + j - 18;
            if (ro >= 0 && ro < 32) acc[ro] = fmaf(taps[j], v, acc[ro]);
        }
    }
}

// ================= interior pipelined helpers =================
template<int NU>
__device__ __forceinline__ void load_pairs(float* buf,
    const float* __restrict__ pEA, const float* __restrict__ pEB,
    const float* __restrict__ pOA, const float* __restrict__ pOB,
    int vof)
{
    #pragma unroll
    for (int u = 0; u < NU; ++u) {
        buf[4*u+0] = pEA[vof + u * 128];
        buf[4*u+1] = pEB[vof + u * 128];
        buf[4*u+2] = pOA[vof + u * 128];
        buf[4*u+3] = pOB[vof + u * 128];
    }
}

template<int L, int EPI0, int UB, int NU>
__device__ __forceinline__ void consume_pairs(float (&acc)[32], const float* buf,
                                              float sgn, const float* __restrict__ taps)
{
    #pragma unroll
    for (int u = 0; u < NU; ++u) {
        float ve = (buf[4*u+0] + buf[4*u+1]) * IS2;
        float vo = (buf[4*u+2] - buf[4*u+3]) * sgn;
        const int pi = EPI0 + 2 * (UB + u);
        #pragma unroll
        for (int j = 0; j < L; ++j) {
            int ro = pi + j - (L - 1);
            if (ro >= 0 && ro < 32) acc[ro] = fmaf(taps[j], ve, acc[ro]);
        }
        #pragma unroll
        for (int j = 0; j < L; ++j) {
            int ro = pi + 1 + j - (L - 1);
            if (ro >= 0 && ro < 32) acc[ro] = fmaf(taps[j], vo, acc[ro]);
        }
    }
}

// depth-2 pipelined c2q column filter: chunks {N0,C,C,C,C}, 3 rotating buffers.
template<int L, int EPI0, int NPT, int C>
__device__ __forceinline__ void c2q_pipe3(
    float (&acc)[32],
    const float* __restrict__ pEA, const float* __restrict__ pEB,
    const float* __restrict__ pOA, const float* __restrict__ pOB,
    int vof, float sgn, const float* __restrict__ taps)
{
    constexpr int N0 = NPT - 4 * C;
    static_assert(N0 > 0 && N0 <= 8, "chunking");
    constexpr int A0 = 0, B0 = N0, C0 = N0 + C, A1 = N0 + 2 * C, B1 = N0 + 3 * C;
    float bufA[4 * ((N0 > C) ? N0 : C)], bufB[4 * C], bufC[4 * C];
    load_pairs<N0>(bufA, pEA, pEB, pOA, pOB, vof + A0 * 128);
    SB();
    load_pairs<C>(bufB, pEA, pEB, pOA, pOB, vof + B0 * 128);
    SB();
    load_pairs<C>(bufC, pEA, pEB, pOA, pOB, vof + C0 * 128);
    SB();
    consume_pairs<L, EPI0, A0, N0>(acc, bufA, sgn, taps);
    SB();
    load_pairs<C>(bufA, pEA, pEB, pOA, pOB, vof + A1 * 128);
    SB();
    consume_pairs<L, EPI0, B0, C>(acc, bufB, sgn, taps);
    SB();
    load_pairs<C>(bufB, pEA, pEB, pOA, pOB, vof + B1 * 128);
    SB();
    consume_pairs<L, EPI0, C0, C>(acc, bufC, sgn, taps);
    SB();
    consume_pairs<L, EPI0, A1, C>(acc, bufA, sgn, taps);
    SB();
    consume_pairs<L, EPI0, B1, C>(acc, bufB, sgn, taps);
}

template<int NT>
__device__ __forceinline__ void load_rows(float* buf, const float* __restrict__ p, int t0)
{
    #pragma unroll
    for (int t = 0; t < NT; ++t) buf[t] = p[(t0 + t) * 256];
}

template<int TB, int NT>
__device__ __forceinline__ void consume_rows(float (&acc)[32], const float* buf,
                                             const float* __restrict__ taps)
{
    #pragma unroll
    for (int t = 0; t < NT; ++t) {
        float v = buf[t];
        const int pi = TB + t;
        #pragma unroll
        for (int j = 0; j < 13; ++j) {
            int ro = pi + j - 12;
            if (ro >= 0 && ro < 32) acc[ro] = fmaf(taps[j], v, acc[ro]);
        }
    }
}

// depth-2 Yl pipe: 44 rows in chunks {4,10,10,10,10}, 3 rotating buffers
__device__ __forceinline__ void yl_pipe3(float (&acc)[32], const float* __restrict__ p,
                                         const float* __restrict__ g0)
{
    float bufA[10], bufB[10], bufC[10];
    load_rows<4>(bufA, p, 0);
    SB();
    load_rows<10>(bufB, p, 4);
    SB();
    load_rows<10>(bufC, p, 14);
    SB();
    consume_rows<0, 4>(acc, bufA, g0);
    SB();
    load_rows<10>(bufA, p, 24);
    SB();
    consume_rows<4, 10>(acc, bufB, g0);
    SB();
    load_rows<10>(bufB, p, 34);
    SB();
    consume_rows<14, 10>(acc, bufC, g0);
    SB();
    consume_rows<24, 10>(acc, bufA, g0);
    SB();
    consume_rows<34, 10>(acc, bufB, g0);
}

extern "C" __global__
__attribute__((amdgpu_flat_work_group_size(512, 512), amdgpu_waves_per_eu(4, 4)))
void dtcwt_inv(
    const float* __restrict__ Yl, const float* __restrict__ Yhr,
    const float* __restrict__ Yhi,
    const float* __restrict__ g0, const float* __restrict__ g1,
    const float* __restrict__ g2, float* __restrict__ out)
{
    // sU[0] = t1a (+t1b added after barrier1), sU[1] = t2 (hl), sU[2] = t3 (hh)
    __shared__ __align__(16) float sU[3][32][PW];   // 34560 B

    const int tid = threadIdx.x;
    // bijective XCD swizzle: 16384 = 8 x 2048
    const int wg  = blockIdx.x;
    const int swz = (wg & 7) * 2048 + (wg >> 3);
    const int plane = swz >> 5;
    const int bt = swz & 31;
    const int bx = bt & 3;
    const int by = bt >> 2;
    const int r0 = by * 32;
    const int c0 = bx * 64;

    const float* ylp = Yl  + (size_t)plane * 65536;
    const float* yhr = Yhr + (size_t)plane * 6 * 16384;
    const float* yhi = Yhi + (size_t)plane * 6 * 16384;

    const bool rowInterior = (by >= 1) && (by <= 6);

    const int role = tid >> 7;
    const int lr   = tid & 127;

    float acc[32];
    #pragma unroll
    for (int i = 0; i < 32; ++i) acc[i] = 0.0f;
    int ti = -1;

    if (rowInterior) {
        if (role == 0) {
            if (lr < 76) {
                ti = lr + 6;
                int cc = symidx(c0 + lr - 6, 256);
                yl_pipe3(acc, ylp + (r0 - 6) * 256 + cc, g0);
            }
        } else if (role == 1) {
            if (lr < 76) {                        // t1b = col_g1(lh), bands 0,5
                ti = lr + 6;
                int cc = symidx(c0 + lr - 6, 256);
                int cp = cc & 1, j2 = cc >> 1;
                const float* pE = cp ? yhi : yhr;
                const float* pO = cp ? yhr : yhi;
                float sgn = cp ? -IS2 : IS2;
                int vof = ((r0 - 10) >> 1) * 128 + j2;
                c2q_pipe3<19, -1, 26, 5>(acc,
                    pE + 0 * 16384, pE + 5 * 16384,
                    pO + 0 * 16384, pO + 5 * 16384, vof, sgn, g1);
            }
        } else if (role == 2) {
            if (lr < 82) {                        // t2 = col_g0(hl), bands 2,3
                ti = lr + 3;
                int cc = symidx(c0 + lr - 9, 256);
                int cp = cc & 1, j2 = cc >> 1;
                const float* pE = cp ? yhi : yhr;
                const float* pO = cp ? yhr : yhi;
                float sgn = cp ? -IS2 : IS2;
                int vof = ((r0 - 6) >> 1) * 128 + j2;
                c2q_pipe3<13, 0, 22, 5>(acc,
                    pE + 2 * 16384, pE + 3 * 16384,
                    pO + 2 * 16384, pO + 3 * 16384, vof, sgn, g0);
            }
        } else {
            if (lr < 76) {                        // t3 = col_g2(hh), bands 1,4
                ti = lr + 6;
                int cc = symidx(c0 + lr - 6, 256);
                int cp = cc & 1, j2 = cc >> 1;
                const float* pE = cp ? yhi : yhr;
                const float* pO = cp ? yhr : yhi;
                float sgn = cp ? -IS2 : IS2;
                int vof = ((r0 - 6) >> 1) * 128 + j2;
                c2q_pipe3<13, 0, 22, 5>(acc,
                    pE + 1 * 16384, pE + 4 * 16384,
                    pO + 1 * 16384, pO + 4 * 16384, vof, sgn, g2);
            }
        }
    } else {
        // ---------- border stage 1 (r1 path, handles row reflection) ----------
        if (role == 0) {
            if (lr < 76) {
                ti = lr + 6;
                int cc = symidx(c0 + ti - 12, 256);
                col13_yl(acc, ylp, g0, r0, cc);
            }
        } else if (role == 1) {
            if (lr < 76) {
                ti = lr + 6;
                int cc = symidx(c0 + ti - 12, 256);
                col19_c2q(acc, yhr, yhi, g1, r0, cc);
            }
        } else if (role == 2) {
            if (lr < 82) {
                ti = lr + 3;
                int cc = symidx(c0 + ti - 12, 256);
                col13_c2q(acc, yhr, yhi, 2, 3, g0, r0, cc);
            }
        } else {
            if (lr < 76) {
                ti = lr + 6;
                int cc = symidx(c0 + ti - 12, 256);
                col13_c2q(acc, yhr, yhi, 1, 4, g2, r0, cc);
            }
        }
    }

    // direct writers: role0 -> sU[0], role2 -> sU[1], role3 -> sU[2]
    if (ti >= 0 && role != 1) {
        const int bi = (role == 0) ? 0 : (role == 2 ? 1 : 2);
        #pragma unroll
        for (int ro = 0; ro < 32; ++ro) sU[bi][ro][ti] = acc[ro];
    }
    __syncthreads();

    // deferred add: lh accumulates into t1 buffer (2 waves only)
    if (role == 1 && ti >= 0) {
        #pragma unroll
        for (int ro = 0; ro < 32; ++ro) sU[0][ro][ti] += acc[ro];
    }

    // meanwhile all waves prefetch w2/w3 (untouched buffers)
    const int cg = tid & 15;
    const int r2 = tid >> 4;
    const int cb = 4 * cg;

    float w2v[28];
    #pragma unroll
    for (int k = 0; k < 14; ++k) {
        float2 a = *(const float2*)&sU[1][r2][cb + 2 * k];
        w2v[2*k] = a.x; w2v[2*k+1] = a.y;
    }
    float w3v[20];
    #pragma unroll
    for (int k = 0; k < 10; ++k) {
        float2 a = *(const float2*)&sU[2][r2][cb + 4 + 2 * k];
        w3v[2*k] = a.x; w3v[2*k+1] = a.y;
    }
    __syncthreads();

    float w1v[20];
    #pragma unroll
    for (int k = 0; k < 10; ++k) {
        float2 a = *(const float2*)&sU[0][r2][cb + 4 + 2 * k];
        w1v[2*k] = a.x; w1v[2*k+1] = a.y;
    }

    float4 res;
    float* op = (float*)&res;
    #pragma unroll
    for (int q = 0; q < 4; ++q) {
        float s = 0.0f;
        #pragma unroll
        for (int j = 0; j < 13; ++j) s = fmaf(g0[j], w1v[q + 14 - j], s);
        #pragma unroll
        for (int j = 0; j < 19; ++j) s = fmaf(g1[j], w2v[q + 21 - j], s);
        #pragma unroll
        for (int j = 0; j < 13; ++j) s = fmaf(g2[j], w3v[q + 14 - j], s);
        op[q] = s;
    }
    *(float4*)&out[(size_t)plane * 65536 + (size_t)(r0 + r2) * 256 + (c0 + cb)] = res;
}

extern "C" void kernel_launch(void* const* d_in, const int* in_sizes, int n_in,
                              void* d_out, int out_size, void* d_ws, size_t ws_size,
                              hipStream_t stream) {
    const float* Yl  = (const float*)d_in[0];
    const float* Yhr = (const float*)d_in[1];
    const float* Yhi = (const float*)d_in[2];
    const float* g0  = (const float*)d_in[3];
    const float* g1  = (const float*)d_in[4];
    const float* g2  = (const float*)d_in[5];
    float* out = (float*)d_out;

    dim3 grid(16384, 1, 1);
    dim3 block(512, 1, 1);
    dtcwt_inv<<<grid, block, 0, stream>>>(Yl, Yhr, Yhi, g0, g1, g2, out);
}